// Round 3
// baseline (245.886 us; speedup 1.0000x reference)
//
#include <hip/hip_runtime.h>
#include <math.h>

// out[tok, d] = cos(dot(x[tok,:], W1) + b1) * cos(phi) * W2[d] + b2[d]
// D = 1024, tokens = B*S = 32768 (fixed by reference shape).
//
// Round 2: identical structure to round-1 submission (4 tokens/wave, all 16
// x-loads issued up front, 4 independent butterfly-reduce chains, nt stores).
// Only change: use clang ext_vector float4 ("f4") instead of HIP_vector_type
// float4 — __builtin_nontemporal_store only accepts scalar/ext_vector types.

#define EMBED_D 1024
#define NTOK    (8 * 4096)
#define TPW     4                      // tokens per wave
#define TOK_PER_BLOCK (4 * TPW)        // 4 waves/block

typedef float f4 __attribute__((ext_vector_type(4)));

__global__ __launch_bounds__(256) void ffq_kernel(
    const float* __restrict__ x,
    const float* __restrict__ W1,
    const float* __restrict__ b1,
    const float* __restrict__ phi,
    const float* __restrict__ W2,
    const float* __restrict__ b2,
    float* __restrict__ out)
{
    const int lane = threadIdx.x & 63;
    const int wib  = threadIdx.x >> 6;                 // wave in block: 0..3
    const int tok0 = (blockIdx.x * 4 + wib) * TPW;     // first of this wave's 4 tokens

    // ---- issue the 16 x-loads first: these are the HBM misses we must overlap ----
    // row = 256 f4; lane l covers chunks {c*64+l}.
    const f4* xb = (const f4*)x + (size_t)tok0 * (EMBED_D / 4);
    f4 xv[TPW][4];
    #pragma unroll
    for (int t = 0; t < TPW; ++t)
        #pragma unroll
        for (int c = 0; c < 4; ++c)
            xv[t][c] = xb[t * (EMBED_D / 4) + c * 64 + lane];

    // ---- broadcast operands (L2/L3-hit after first wave round) ----
    const f4* w14 = (const f4*)W1;
    const f4* w24 = (const f4*)W2;
    const f4* b24 = (const f4*)b2;
    f4 w1r[4], w2r[4], b2r[4];
    #pragma unroll
    for (int c = 0; c < 4; ++c) {
        w1r[c] = w14[c * 64 + lane];
        w2r[c] = w24[c * 64 + lane];
        b2r[c] = b24[c * 64 + lane];
    }
    const float cphi = cosf(phi[0]);
    const float b1v  = b1[0];

    // ---- 4 independent dot-product partials ----
    float v[TPW];
    #pragma unroll
    for (int t = 0; t < TPW; ++t) {
        float s = 0.f;
        #pragma unroll
        for (int c = 0; c < 4; ++c) {
            s = fmaf(xv[t][c].x, w1r[c].x, s);
            s = fmaf(xv[t][c].y, w1r[c].y, s);
            s = fmaf(xv[t][c].z, w1r[c].z, s);
            s = fmaf(xv[t][c].w, w1r[c].w, s);
        }
        v[t] = s;
    }

    // ---- 4 interleaved butterfly reductions (independent chains pipeline) ----
    #pragma unroll
    for (int m = 32; m > 0; m >>= 1) {
        #pragma unroll
        for (int t = 0; t < TPW; ++t)
            v[t] += __shfl_xor(v[t], m, 64);
    }

    float q[TPW];
    #pragma unroll
    for (int t = 0; t < TPW; ++t)
        q[t] = cosf(v[t] + b1v) * cphi;

    // ---- stores: q broadcast within wave, coalesced f4, non-temporal ----
    f4* ob = (f4*)out + (size_t)tok0 * (EMBED_D / 4);
    #pragma unroll
    for (int t = 0; t < TPW; ++t) {
        #pragma unroll
        for (int c = 0; c < 4; ++c) {
            f4 o;
            o.x = fmaf(q[t], w2r[c].x, b2r[c].x);
            o.y = fmaf(q[t], w2r[c].y, b2r[c].y);
            o.z = fmaf(q[t], w2r[c].z, b2r[c].z);
            o.w = fmaf(q[t], w2r[c].w, b2r[c].w);
            __builtin_nontemporal_store(o, &ob[t * (EMBED_D / 4) + c * 64 + lane]);
        }
    }
}

extern "C" void kernel_launch(void* const* d_in, const int* in_sizes, int n_in,
                              void* d_out, int out_size, void* d_ws, size_t ws_size,
                              hipStream_t stream) {
    const float* x   = (const float*)d_in[0];
    const float* W1  = (const float*)d_in[1];
    const float* b1  = (const float*)d_in[2];
    const float* phi = (const float*)d_in[3];
    const float* W2  = (const float*)d_in[4];
    const float* b2  = (const float*)d_in[5];
    float* out = (float*)d_out;

    // 32768 tokens / 16 per block = 2048 blocks, one shot, no bounds checks.
    ffq_kernel<<<NTOK / TOK_PER_BLOCK, 256, 0, stream>>>(x, W1, b1, phi, W2, b2, out);
}

// Round 4
// 236.189 us; speedup vs baseline: 1.0411x; 1.0411x over previous
//
#include <hip/hip_runtime.h>
#include <math.h>

// out[tok, d] = cos(dot(x[tok,:], W1) + b1) * cos(phi) * W2[d] + b2[d]
// D = 1024, tokens = B*S = 32768 (fixed by reference shape).
//
// Round 4: SPLIT into two pure-stream kernels to break the per-wave
// load->reduce->cos->store serial chain that kept the fused kernel
// latency-bound at ~80us (VALUBusy 5%, HBM 30%, both pipes idle):
//
//   phase 1 (ffq_theta): q[tok] = cos(x.W1 + b1)*cos(phi)
//       reads 128 MiB of x, writes 128 KiB of q into d_ws.
//       Pure read+reduce stream; the 4B/token store gates nothing.
//   phase 2 (ffq_out):   out[tok,:] = q[tok]*W2 + b2
//       reads 128 KiB of q (L2-hit) + 8 KiB W2/b2, writes 128 MiB.
//       Structurally identical to the rocclr fill kernel (6.7 TB/s here).
//
// q lives in the workspace; fully overwritten each launch before being read.

#define EMBED_D 1024
#define NTOK    (8 * 4096)

typedef float f4 __attribute__((ext_vector_type(4)));

// ---------------- phase 1: theta/q ----------------
// 1 wave per token, 4 waves per block, 8192 blocks. No LDS, no barriers.
__global__ __launch_bounds__(256) void ffq_theta(
    const float* __restrict__ x,
    const float* __restrict__ W1,
    const float* __restrict__ b1,
    const float* __restrict__ phi,
    float* __restrict__ q_ws)
{
    const int lane = threadIdx.x & 63;
    const int wib  = threadIdx.x >> 6;
    const int tok  = blockIdx.x * 4 + wib;

    // row = 256 f4; lane l covers chunks {c*64+l : c=0..3}. Issue all 4 first.
    const f4* x4 = (const f4*)x + (size_t)tok * (EMBED_D / 4);
    f4 xv[4];
    #pragma unroll
    for (int c = 0; c < 4; ++c) xv[c] = x4[c * 64 + lane];

    const f4* w14 = (const f4*)W1;
    f4 w1r[4];
    #pragma unroll
    for (int c = 0; c < 4; ++c) w1r[c] = w14[c * 64 + lane];

    float s = 0.f;
    #pragma unroll
    for (int c = 0; c < 4; ++c) {
        s = fmaf(xv[c].x, w1r[c].x, s);
        s = fmaf(xv[c].y, w1r[c].y, s);
        s = fmaf(xv[c].z, w1r[c].z, s);
        s = fmaf(xv[c].w, w1r[c].w, s);
    }

    // butterfly: all lanes end with the row sum
    #pragma unroll
    for (int m = 32; m > 0; m >>= 1)
        s += __shfl_xor(s, m, 64);

    if (lane == 0)
        q_ws[tok] = cosf(s + b1[0]) * cosf(phi[0]);
}

// ---------------- phase 2: rank-1 expand ----------------
// 4 token rows per block, 8192 blocks. Thread t owns f4-chunk t of each row.
__global__ __launch_bounds__(256) void ffq_out(
    const float* __restrict__ q_ws,
    const float* __restrict__ W2,
    const float* __restrict__ b2,
    float* __restrict__ out)
{
    const int t = threadIdx.x;                    // 0..255 = f4 index in row
    const int b = blockIdx.x;                     // 4 tokens per block

    const f4 qv  = ((const f4*)q_ws)[b];          // q[4b..4b+3], uniform (L2)
    const f4 w2v = ((const f4*)W2)[t];
    const f4 b2v = ((const f4*)b2)[t];

    f4* ob = (f4*)out + (size_t)b * 4 * (EMBED_D / 4);
    const float qq[4] = { qv.x, qv.y, qv.z, qv.w };

    #pragma unroll
    for (int tt = 0; tt < 4; ++tt) {
        f4 o;
        o.x = fmaf(qq[tt], w2v.x, b2v.x);
        o.y = fmaf(qq[tt], w2v.y, b2v.y);
        o.z = fmaf(qq[tt], w2v.z, b2v.z);
        o.w = fmaf(qq[tt], w2v.w, b2v.w);
        __builtin_nontemporal_store(o, &ob[tt * (EMBED_D / 4) + t]);
    }
}

extern "C" void kernel_launch(void* const* d_in, const int* in_sizes, int n_in,
                              void* d_out, int out_size, void* d_ws, size_t ws_size,
                              hipStream_t stream) {
    const float* x   = (const float*)d_in[0];
    const float* W1  = (const float*)d_in[1];
    const float* b1  = (const float*)d_in[2];
    const float* phi = (const float*)d_in[3];
    const float* W2  = (const float*)d_in[4];
    const float* b2  = (const float*)d_in[5];
    float* out = (float*)d_out;
    float* q_ws = (float*)d_ws;        // 32768 floats = 128 KiB of workspace

    // phase 1: 32768 tokens / 4 per block = 8192 blocks
    ffq_theta<<<NTOK / 4, 256, 0, stream>>>(x, W1, b1, phi, q_ws);
    // phase 2: 32768 rows / 4 per block = 8192 blocks (stream-ordered after p1)
    ffq_out<<<NTOK / 4, 256, 0, stream>>>(q_ws, W2, b2, out);
}